// Round 6
// baseline (261.317 us; speedup 1.0000x reference)
//
#include <hip/hip_runtime.h>

#define SEQ 1024
#define HID 2048
#define DIN 4096
#define NST 16
#define RNK 128
#define CHN 64
#define CLEN 16

typedef __attribute__((ext_vector_type(4))) float f32x4;
typedef __attribute__((ext_vector_type(4))) __bf16 bf16x4v;
typedef __attribute__((ext_vector_type(8))) __bf16 bf16x8v;
typedef __attribute__((ext_vector_type(8))) unsigned short u16x8;

#define GPTR(p) ((const __attribute__((address_space(1))) void*)(p))
#define LPTR(p) ((__attribute__((address_space(3))) void*)(p))

__device__ __forceinline__ unsigned short f2bf(float v) {
  unsigned u = __builtin_bit_cast(unsigned, v);
  u = (u + 0x7fffu + ((u >> 16) & 1u)) >> 16;
  return (unsigned short)u;
}
__device__ __forceinline__ float softplus_f(float x) {
  return (x > 20.f) ? x : log1pf(__expf(x));
}
__device__ __forceinline__ float silu_f(float x) {
  return x / (1.f + __expf(-x));
}

// ---------------- fp32 -> bf16 conversions, one launch, 8 elems/thread ----------------
#define CV_NX  (SEQ*HID)
#define CV_NW  (DIN*HID)
#define CV_NDT (RNK*DIN)
#define CV_NB  (NST*DIN)
#define CV_NPD (32*DIN)
#define CV_NWO (HID*DIN)
#define CV_TOT (CV_NX + 2*CV_NW + CV_NDT + 2*CV_NB + CV_NPD + CV_NDT + CV_NWO)

// All segment sizes are multiples of 512, so no wave straddles a segment
// boundary (64 lanes x 8 elems = 512). 32B load / 16B store per lane.
__global__ __launch_bounds__(256) void cvt_all(
    const float* __restrict__ x, const float* __restrict__ wis,
    const float* __restrict__ wig, const float* __restrict__ wdt,
    const float* __restrict__ wb, const float* __restrict__ wc,
    const float* __restrict__ wdtp, const float* __restrict__ wout,
    unsigned short* __restrict__ x_bf, unsigned short* __restrict__ wis_bf,
    unsigned short* __restrict__ wig_bf, unsigned short* __restrict__ wcat_bf,
    unsigned short* __restrict__ wdtp_bf, unsigned short* __restrict__ wout_bf)
{
  size_t j = ((size_t)blockIdx.x * 256 + threadIdx.x) * 8;
  const float* src = nullptr; unsigned short* dst;
  if (j < CV_NX) { src = x + j; dst = x_bf + j; }
  else if ((j -= CV_NX) < CV_NW) { src = wis + j; dst = wis_bf + j; }
  else if ((j -= CV_NW) < CV_NW) { src = wig + j; dst = wig_bf + j; }
  else if ((j -= CV_NW) < CV_NDT) { src = wdt + j; dst = wcat_bf + j; }
  else if ((j -= CV_NDT) < CV_NB) { src = wb + j; dst = wcat_bf + (size_t)128*DIN + j; }
  else if ((j -= CV_NB) < CV_NB) { src = wc + j; dst = wcat_bf + (size_t)144*DIN + j; }
  else if ((j -= CV_NB) < CV_NPD) { dst = wcat_bf + (size_t)160*DIN + j; }
  else if ((j -= CV_NPD) < CV_NDT) { src = wdtp + j; dst = wdtp_bf + j; }
  else { j -= CV_NDT; src = wout + j; dst = wout_bf + j; }
  u16x8 o = {};
  if (src) {
    f32x4 a = *(const f32x4*)src;
    f32x4 b = *(const f32x4*)(src + 4);
#pragma unroll
    for (int i = 0; i < 4; i++) { o[i] = f2bf(a[i]); o[4 + i] = f2bf(b[i]); }
  }
  *(u16x8*)dst = o;
}

// ---------------- pipelined NT GEMM: 128x128 tile, BK=64, A in registers ----------------
// A: [M][Kstride] bf16, B: [N][Kstride] bf16, C: [M][N] fp32.
// R4 audit: 16 waves/CU x 16 ds_read_b128/step = ~3070 cyc/step at ~85 B/cyc
// LDS-read throughput == observed 3345 cyc/step -> LDS-bound. Fix: A-tile
// never touches LDS. Each wave loads its MFMA A-fragments directly
// global->VGPR (16 rows x 64 B segments; A is small and L2-hot), register
// double-buffered (arE/arO, statically indexed per rule #20). LDS carries
// only B (2 x 16 KB buffers): per-CU LDS reads halve to ~1700 cyc/step.
// Schedule per K-step (unchanged): vmcnt(0); s_barrier; issue B-stage(t+1)
// + A-load(t+1); ds_read B(t); 32x MFMA with A(t) regs.
// T2 swizzle on B only (rows 128 B = 8 slots): slot s at row r holds k-chunk
// s ^ (r&7); linear LDS dest + inverse-swz global source + swz read.
// grid.z>1 => split-K. XCD swizzle needs gridDim.x*gridDim.y % 8 == 0.
// Requires Kiter % 128 == 0 (nt even).
template<int EPI>
__global__ __launch_bounds__(256, 2) void gemm128(
    const unsigned short* __restrict__ Ag, const unsigned short* __restrict__ Bg,
    float* __restrict__ Cg, const float* __restrict__ bias,
    int Msz, int Nsz, int Kstride, int Kiter)
{
  __shared__ __align__(16) unsigned short Bs[2][128 * 64];
  const int kz = blockIdx.z;
  Ag += (size_t)kz * Kiter;
  Bg += (size_t)kz * Kiter;
  Cg += (size_t)kz * Msz * Nsz;
  const int nwg = gridDim.x * gridDim.y;
  const int orig = blockIdx.y * gridDim.x + blockIdx.x;
  const int swz = (orig & 7) * (nwg >> 3) + (orig >> 3);
  const int bx = swz % gridDim.x, by = swz / gridDim.x;
  const int tid = threadIdx.x;
  const int m0 = bx * 128, n0 = by * 128;
  const int lane = tid & 63, w = tid >> 6;
  const int wm = w >> 1, wn = w & 1;
  const int lg = lane >> 4, lr = lane & 15;
  // B staging: wave w stages B rows w*32..w*32+31; 16B per lane.
  const int srow = w * 32 + (lane >> 3);
  const int sslot = (lane & 7) ^ (lane >> 3);      // swizzled global k-slot
  const unsigned short* Bg0 = Bg + (size_t)(n0 + srow) * Kstride + sslot * 8;
  const int ldso = w * 2048;                        // ushort idx of wave chunk

  auto stageB = [&](int b, int k0) {
#pragma unroll
    for (int i = 0; i < 4; i++)
      __builtin_amdgcn_global_load_lds(GPTR(Bg0 + (size_t)(i * 8) * Kstride + k0),
                                       LPTR(&Bs[b][ldso + i * 512]), 16, 0, 0);
  };

  // A direct-to-register loads: lane (lg,lr) of wave quadrant wm reads
  // A[m0 + wm*64 + mi*16 + lr][k0 + kk*32 + lg*8 .. +8].
  const unsigned short* Ab = Ag + (size_t)(m0 + wm * 64 + lr) * Kstride + lg * 8;
  auto loadA = [&](bf16x8v (&ar)[8], int k0) {
#pragma unroll
    for (int mi = 0; mi < 4; mi++)
#pragma unroll
      for (int kk = 0; kk < 2; kk++)
        ar[mi * 2 + kk] = *(const bf16x8v*)(Ab + (size_t)(mi * 16) * Kstride + k0 + kk * 32);
  };

  const int rsw = lr & 7;                           // B read-side XOR key
  f32x4 acc[4][4] = {};

  auto compute = [&](int b, bf16x8v (&ar)[8]) {
    bf16x8v bf0[4], bf1[4];
#pragma unroll
    for (int ni = 0; ni < 4; ni++) {
      const int row = (wn * 64 + ni * 16 + lr) * 64;
      bf0[ni] = *(const bf16x8v*)&Bs[b][row + (lg ^ rsw) * 8];
      bf1[ni] = *(const bf16x8v*)&Bs[b][row + ((4 + lg) ^ rsw) * 8];
    }
#pragma unroll
    for (int mi = 0; mi < 4; mi++)
#pragma unroll
      for (int ni = 0; ni < 4; ni++)
        acc[mi][ni] = __builtin_amdgcn_mfma_f32_16x16x32_bf16(ar[mi * 2 + 0], bf0[ni], acc[mi][ni], 0, 0, 0);
#pragma unroll
    for (int mi = 0; mi < 4; mi++)
#pragma unroll
      for (int ni = 0; ni < 4; ni++)
        acc[mi][ni] = __builtin_amdgcn_mfma_f32_16x16x32_bf16(ar[mi * 2 + 1], bf1[ni], acc[mi][ni], 0, 0, 0);
  };

  const int nt = Kiter >> 6;                        // even by contract
  bf16x8v arE[8], arO[8];
  stageB(0, 0);
  loadA(arE, 0);
  for (int t2 = 0; t2 < nt; t2 += 2) {
    // even step: consume (Bs[0], arE); prefetch t2+1 into (Bs[1], arO)
    asm volatile("s_waitcnt vmcnt(0)" ::: "memory");
    __builtin_amdgcn_s_barrier();
    asm volatile("" ::: "memory");
    if (t2 + 1 < nt) { stageB(1, (t2 + 1) * 64); loadA(arO, (t2 + 1) * 64); }
    compute(0, arE);
    // odd step: consume (Bs[1], arO); prefetch t2+2 into (Bs[0], arE)
    if (t2 + 1 < nt) {
      asm volatile("s_waitcnt vmcnt(0)" ::: "memory");
      __builtin_amdgcn_s_barrier();
      asm volatile("" ::: "memory");
      if (t2 + 2 < nt) { stageB(0, (t2 + 2) * 64); loadA(arE, (t2 + 2) * 64); }
      compute(1, arO);
    }
  }
#pragma unroll
  for (int mi = 0; mi < 4; mi++) {
#pragma unroll
    for (int ni = 0; ni < 4; ni++) {
      const int col = n0 + wn * 64 + ni * 16 + lr;
#pragma unroll
      for (int r = 0; r < 4; r++) {
        const int row = m0 + wm * 64 + mi * 16 + lg * 4 + r;
        float v = acc[mi][ni][r];
        if (EPI == 1) v = softplus_f(v + bias[col]);
        Cg[(size_t)row * Nsz + col] = v;
      }
    }
  }
}

// ---------------- 128x64 NT GEMM, VGPR-staged (ts/B/C projection + dt-proj) ----------------
template<int EPI>
__global__ __launch_bounds__(256) void gemm_nt(
    const unsigned short* __restrict__ Ag, const unsigned short* __restrict__ Bg,
    float* __restrict__ Cg, const float* __restrict__ bias,
    int Msz, int Nsz, int Kstride, int Kiter)
{
  __shared__ __align__(16) unsigned short As[128][40];
  __shared__ __align__(16) unsigned short Bs[64][40];
  const int kz = blockIdx.z;
  Ag += (size_t)kz * Kiter;
  Bg += (size_t)kz * Kiter;
  Cg += (size_t)kz * Msz * Nsz;
  const int tid = threadIdx.x;
  const int m0 = blockIdx.x * 128, n0 = blockIdx.y * 64;
  const int lane = tid & 63, w = tid >> 6;
  const int wm = w >> 1, wn = w & 1;
  const int lg = lane >> 4, lr = lane & 15;
  const int r4 = tid >> 2, c8 = (tid & 3) * 8;
  f32x4 acc[4][2] = {};
  for (int k0 = 0; k0 < Kiter; k0 += 32) {
    uint4 a0 = *(const uint4*)(Ag + (size_t)(m0 + r4) * Kstride + k0 + c8);
    uint4 a1 = *(const uint4*)(Ag + (size_t)(m0 + 64 + r4) * Kstride + k0 + c8);
    uint4 b0 = *(const uint4*)(Bg + (size_t)(n0 + r4) * Kstride + k0 + c8);
    *(uint4*)&As[r4][c8] = a0;
    *(uint4*)&As[64 + r4][c8] = a1;
    *(uint4*)&Bs[r4][c8] = b0;
    __syncthreads();
    bf16x8v af[4], bfr[2];
#pragma unroll
    for (int mi = 0; mi < 4; mi++) {
      const int row = wm * 64 + mi * 16 + lr;
      bf16x4v lo = *(const bf16x4v*)&As[row][4 * lg];
      bf16x4v hi = *(const bf16x4v*)&As[row][16 + 4 * lg];
      af[mi] = __builtin_shufflevector(lo, hi, 0, 1, 2, 3, 4, 5, 6, 7);
    }
#pragma unroll
    for (int ni = 0; ni < 2; ni++) {
      const int row = wn * 32 + ni * 16 + lr;
      bf16x4v lo = *(const bf16x4v*)&Bs[row][4 * lg];
      bf16x4v hi = *(const bf16x4v*)&Bs[row][16 + 4 * lg];
      bfr[ni] = __builtin_shufflevector(lo, hi, 0, 1, 2, 3, 4, 5, 6, 7);
    }
#pragma unroll
    for (int mi = 0; mi < 4; mi++)
#pragma unroll
      for (int ni = 0; ni < 2; ni++)
        acc[mi][ni] = __builtin_amdgcn_mfma_f32_16x16x32_bf16(af[mi], bfr[ni], acc[mi][ni], 0, 0, 0);
    __syncthreads();
  }
#pragma unroll
  for (int mi = 0; mi < 4; mi++) {
#pragma unroll
    for (int ni = 0; ni < 2; ni++) {
      const int col = n0 + wn * 32 + ni * 16 + lr;
#pragma unroll
      for (int r = 0; r < 4; r++) {
        const int row = m0 + wm * 64 + mi * 16 + lg * 4 + r;
        float v = acc[mi][ni][r];
        if (EPI == 1) v = softplus_f(v + bias[col]);
        Cg[(size_t)row * Nsz + col] = v;
      }
    }
  }
}

// ---------------- causal depthwise conv(K=4) + bias + silu; pg stride 8192 ----------------
__global__ __launch_bounds__(256) void conv_silu(
    const float* __restrict__ pg, const float* __restrict__ cw,
    const float* __restrict__ cb, float* __restrict__ hs,
    unsigned short* __restrict__ hs_bf)
{
  int idx = blockIdx.x * 256 + threadIdx.x;  // l*DIN + d
  int l = idx >> 12, d = idx & (DIN - 1);
  float acc = cb[d];
#pragma unroll
  for (int j = 0; j < 4; j++) {
    int ll = l + j - 3;
    float v = (ll >= 0) ? pg[(size_t)ll * 8192 + d] : 0.f;
    acc = fmaf(cw[d * 4 + j], v, acc);
  }
  float r = silu_f(acc);
  hs[idx] = r;
  hs_bf[idx] = f2bf(r);
}

// ---------------- split-K reduce for ts/B/C + ts->bf16 ----------------
__global__ __launch_bounds__(256) void reduce_ts(
    const float* __restrict__ c2p, float* __restrict__ c2,
    unsigned short* __restrict__ ts_bf)
{
  int i = blockIdx.x * 256 + threadIdx.x;  // < SEQ*192
  float s = 0.f;
#pragma unroll
  for (int z = 0; z < 8; z++) s += c2p[(size_t)z * SEQ * 192 + i];
  c2[i] = s;
  int l = i / 192, col = i - l * 192;
  if (col < 128) ts_bf[l * 128 + col] = f2bf(s);
}

// ---------------- split-K reduce for out-proj (x4, float4) ----------------
__global__ __launch_bounds__(256) void reduce_out(
    const float* __restrict__ p, float* __restrict__ out)
{
  int i = (blockIdx.x * 256 + threadIdx.x) * 4;
  float4 a = *(const float4*)&p[i];
#pragma unroll
  for (int z = 1; z < 4; z++) {
    float4 b = *(const float4*)&p[(size_t)z * SEQ * HID + i];
    a.x += b.x; a.y += b.y; a.z += b.z; a.w += b.w;
  }
  *(float4*)&out[i] = a;
}

// ---------------- chunked selective scan ----------------
__global__ __launch_bounds__(256) void scan_phase1(
    const float* __restrict__ dt, const float* __restrict__ hs,
    const float* __restrict__ c2, const float* __restrict__ alog,
    float* __restrict__ Pbuf, float* __restrict__ Sbuf)
{
  __shared__ float B_ch[CLEN][16];
  const int tid = threadIdx.x;
  const int d = blockIdx.x * 256 + tid;
  const int c = blockIdx.y;
  const int l0 = c * CLEN;
  B_ch[tid >> 4][tid & 15] = c2[(size_t)(l0 + (tid >> 4)) * 192 + 128 + (tid & 15)];
  float a[16];
#pragma unroll
  for (int i = 0; i < 16; i++) a[i] = -__expf(alog[(size_t)d * 16 + i]);
  __syncthreads();
  float s[16] = {};
  float P[16];
#pragma unroll
  for (int i = 0; i < 16; i++) P[i] = 1.f;
  for (int t = 0; t < CLEN; t++) {
    float dtv = dt[(size_t)(l0 + t) * DIN + d];
    float u = hs[(size_t)(l0 + t) * DIN + d];
    float w = dtv * u;
#pragma unroll
    for (int n = 0; n < 16; n++) {
      float dA = __expf(a[n] * dtv);
      s[n] = fmaf(dA, s[n], w * B_ch[t][n]);
      P[n] *= dA;
    }
  }
  size_t base = ((size_t)c * DIN + d) * 16;
#pragma unroll
  for (int i = 0; i < 4; i++) {
    *(float4*)&Sbuf[base + 4 * i] = *(float4*)&s[4 * i];
    *(float4*)&Pbuf[base + 4 * i] = *(float4*)&P[4 * i];
  }
}

// phase 2: serial combine; sig written IN-PLACE into Sbuf
__global__ __launch_bounds__(256) void scan_phase2(
    const float* __restrict__ Pbuf, float* __restrict__ Sbuf)
{
  size_t idx = (size_t)blockIdx.x * 256 + threadIdx.x;  // d*16+n
  const size_t stride = (size_t)DIN * 16;
  float s = 0.f;
#pragma unroll 4
  for (int c = 0; c < CHN; c++) {
    float Pv = Pbuf[c * stride + idx];
    float Sv = Sbuf[c * stride + idx];
    Sbuf[c * stride + idx] = s;
    s = fmaf(Pv, s, Sv);
  }
}

// phase 3: re-scan chunk from sig (=Sbuf), y = s.C, fused D + gate, write ygT bf16
__global__ __launch_bounds__(256) void scan_phase3(
    const float* __restrict__ dt, const float* __restrict__ hs,
    const float* __restrict__ pg, const float* __restrict__ c2,
    const float* __restrict__ alog, const float* __restrict__ Dv,
    const float* __restrict__ sig, unsigned short* __restrict__ ygT)
{
  __shared__ float B_ch[CLEN][16], C_ch[CLEN][16];
  const int tid = threadIdx.x;
  const int d = blockIdx.x * 256 + tid;
  const int c = blockIdx.y;
  const int l0 = c * CLEN;
  {
    int t = tid >> 4, n = tid & 15;
    B_ch[t][n] = c2[(size_t)(l0 + t) * 192 + 128 + n];
    C_ch[t][n] = c2[(size_t)(l0 + t) * 192 + 144 + n];
  }
  float a[16];
#pragma unroll
  for (int i = 0; i < 16; i++) a[i] = -__expf(alog[(size_t)d * 16 + i]);
  const float Dd = Dv[d];
  float s[16];
  size_t base = ((size_t)c * DIN + d) * 16;
#pragma unroll
  for (int i = 0; i < 4; i++) *(float4*)&s[4 * i] = *(const float4*)&sig[base + 4 * i];
  __syncthreads();
  for (int t = 0; t < CLEN; t++) {
    float dtv = dt[(size_t)(l0 + t) * DIN + d];
    float u = hs[(size_t)(l0 + t) * DIN + d];
    float g = pg[(size_t)(l0 + t) * 8192 + 4096 + d];
    float w = dtv * u;
    float y = 0.f;
#pragma unroll
    for (int n = 0; n < 16; n++) {
      float dA = __expf(a[n] * dtv);
      s[n] = fmaf(dA, s[n], w * B_ch[t][n]);
      y = fmaf(s[n], C_ch[t][n], y);
    }
    float o = (y + u * Dd) * silu_f(g);
    ygT[(size_t)(l0 + t) * DIN + d] = f2bf(o);
  }
}

extern "C" void kernel_launch(void* const* d_in, const int* in_sizes, int n_in,
                              void* d_out, int out_size, void* d_ws, size_t ws_size,
                              hipStream_t stream) {
  const float* x     = (const float*)d_in[0];
  const float* wis   = (const float*)d_in[1];
  const float* wig   = (const float*)d_in[2];
  const float* convw = (const float*)d_in[3];
  const float* convb = (const float*)d_in[4];
  const float* wdt   = (const float*)d_in[5];
  const float* wb    = (const float*)d_in[6];
  const float* wc    = (const float*)d_in[7];
  const float* wdtp  = (const float*)d_in[8];
  const float* bdtp  = (const float*)d_in[9];
  const float* alog  = (const float*)d_in[10];
  const float* Dv    = (const float*)d_in[11];
  const float* wout  = (const float*)d_in[12];

  char* ws = (char*)d_ws;
  size_t off = 0;
  auto alloc = [&](size_t bytes) { void* p = ws + off; off += (bytes + 255) & ~(size_t)255; return p; };
  unsigned short* x_bf    = (unsigned short*)alloc((size_t)SEQ * HID * 2);
  unsigned short* wis_bf  = (unsigned short*)alloc((size_t)DIN * HID * 2);  // adjacent to wig_bf: one [8192][2048] B matrix
  unsigned short* wig_bf  = (unsigned short*)alloc((size_t)DIN * HID * 2);
  unsigned short* wcat_bf = (unsigned short*)alloc((size_t)192 * DIN * 2);
  unsigned short* wdtp_bf = (unsigned short*)alloc((size_t)DIN * RNK * 2);
  unsigned short* wout_bf = (unsigned short*)alloc((size_t)HID * DIN * 2);
  float* pg    = (float*)alloc((size_t)SEQ * 8192 * 4);  // [SEQ][8192]: cols 0..4095 pre-conv states, 4096..8191 gate
  float* hs2   = (float*)alloc((size_t)SEQ * DIN * 4);   // hs post conv+silu [SEQ][DIN]
  unsigned short* hs_bf = (unsigned short*)alloc((size_t)SEQ * DIN * 2);
  float* c2    = (float*)alloc((size_t)SEQ * 192 * 4);
  float* c2p   = (float*)alloc((size_t)8 * SEQ * 192 * 4);
  unsigned short* ts_bf = (unsigned short*)alloc((size_t)SEQ * RNK * 2);
  float* dtbuf = (float*)alloc((size_t)SEQ * DIN * 4);
  unsigned short* ygT_bf = (unsigned short*)alloc((size_t)SEQ * DIN * 2);
  if (off > ws_size) return;  // workspace too small: fail loudly via validation
  // dead-buffer reuse: wis_bf/wig_bf (16 MB each) dead after in-proj;
  // pg (32 MB) dead after scan_phase3 -> holds the 4 out-proj partials.
  float* Pbuf = (float*)wis_bf;
  float* Sbuf = (float*)wig_bf;   // phase2 overwrites with sig in-place
  float* op_part = pg;            // [4][SEQ][HID] out-proj partials

  // 1) all bf16 conversions (8 elems/thread: 2x float4 load, ushort8 store)
  cvt_all<<<CV_TOT / 2048, 256, 0, stream>>>(x, wis, wig, wdt, wb, wc, wdtp, wout,
                                             x_bf, wis_bf, wig_bf, wcat_bf, wdtp_bf, wout_bf);
  // 2) merged input projection (BK=64, A-in-reg pipelined gemm, XCD swizzle):
  //    pg[SEQ][8192] = x[SEQ][HID] x [wis;wig][8192][HID]
  gemm128<0><<<dim3(SEQ / 128, 8192 / 128), 256, 0, stream>>>(x_bf, wis_bf, pg, nullptr, SEQ, 8192, HID, HID);
  // 3) causal conv + silu + bf16 cast
  conv_silu<<<(SEQ * DIN) / 256, 256, 0, stream>>>(pg, convw, convb, hs2, hs_bf);
  // 4) ts/B/C projections, split-K x8
  gemm_nt<0><<<dim3(SEQ / 128, 192 / 64, 8), 256, 0, stream>>>(hs_bf, wcat_bf, c2p, nullptr, SEQ, 192, DIN, DIN / 8);
  reduce_ts<<<(SEQ * 192) / 256, 256, 0, stream>>>(c2p, c2, ts_bf);
  // 5) dt[SEQ][DIN] = softplus(ts[SEQ][RNK] x Wdtproj[DIN][RNK] + b)
  gemm_nt<1><<<dim3(SEQ / 128, DIN / 64), 256, 0, stream>>>(ts_bf, wdtp_bf, dtbuf, bdtp, SEQ, DIN, RNK, RNK);
  // 6) chunked selective scan (64 chunks of 16)
  scan_phase1<<<dim3(DIN / 256, CHN), 256, 0, stream>>>(dtbuf, hs2, c2, alog, Pbuf, Sbuf);
  scan_phase2<<<(DIN * NST) / 256, 256, 0, stream>>>(Pbuf, Sbuf);
  scan_phase3<<<dim3(DIN / 256, CHN), 256, 0, stream>>>(dtbuf, hs2, pg, c2, alog, Dv, Sbuf, ygT_bf);
  // 7) out-proj split-K x4 (512 wg): op_part[z][SEQ][HID] = ygT x Wout slices (K=1024, nt=16)
  gemm128<0><<<dim3(SEQ / 128, HID / 128, 4), 256, 0, stream>>>(ygT_bf, wout_bf, op_part, nullptr, SEQ, HID, DIN, DIN / 4);
  reduce_out<<<(SEQ * HID) / 1024, 256, 0, stream>>>(op_part, (float*)d_out);
}

// Round 7
// 246.497 us; speedup vs baseline: 1.0601x; 1.0601x over previous
//
#include <hip/hip_runtime.h>

#define SEQ 1024
#define HID 2048
#define DIN 4096
#define NST 16
#define RNK 128
#define CHN 64
#define CLEN 16

typedef __attribute__((ext_vector_type(4))) float f32x4;
typedef __attribute__((ext_vector_type(4))) __bf16 bf16x4v;
typedef __attribute__((ext_vector_type(8))) __bf16 bf16x8v;
typedef __attribute__((ext_vector_type(8))) unsigned short u16x8;

#define GPTR(p) ((const __attribute__((address_space(1))) void*)(p))
#define LPTR(p) ((__attribute__((address_space(3))) void*)(p))

__device__ __forceinline__ unsigned short f2bf(float v) {
  unsigned u = __builtin_bit_cast(unsigned, v);
  u = (u + 0x7fffu + ((u >> 16) & 1u)) >> 16;
  return (unsigned short)u;
}
__device__ __forceinline__ float softplus_f(float x) {
  return (x > 20.f) ? x : log1pf(__expf(x));
}
__device__ __forceinline__ float silu_f(float x) {
  return x / (1.f + __expf(-x));
}

// ---------------- fp32 -> bf16 conversions (small tensors only) ----------------
// Weights wis/wig/wout are now consumed as fp32 directly by gemm128 (B-side
// reg-staged cvt) -- they never get a bf16 copy. Only x + the small
// projection weights are pre-converted.
#define CV_NX  (SEQ*HID)
#define CV_NDT (RNK*DIN)
#define CV_NB  (NST*DIN)
#define CV_NPD (32*DIN)
#define CV_TOT (CV_NX + CV_NDT + 2*CV_NB + CV_NPD + CV_NDT)

// All segment sizes are multiples of 512, so no wave straddles a segment
// boundary (64 lanes x 8 elems = 512). 32B load / 16B store per lane.
__global__ __launch_bounds__(256) void cvt_all(
    const float* __restrict__ x, const float* __restrict__ wdt,
    const float* __restrict__ wb, const float* __restrict__ wc,
    const float* __restrict__ wdtp,
    unsigned short* __restrict__ x_bf, unsigned short* __restrict__ wcat_bf,
    unsigned short* __restrict__ wdtp_bf)
{
  size_t j = ((size_t)blockIdx.x * 256 + threadIdx.x) * 8;
  const float* src = nullptr; unsigned short* dst;
  if (j < CV_NX) { src = x + j; dst = x_bf + j; }
  else if ((j -= CV_NX) < CV_NDT) { src = wdt + j; dst = wcat_bf + j; }
  else if ((j -= CV_NDT) < CV_NB) { src = wb + j; dst = wcat_bf + (size_t)128*DIN + j; }
  else if ((j -= CV_NB) < CV_NB) { src = wc + j; dst = wcat_bf + (size_t)144*DIN + j; }
  else if ((j -= CV_NB) < CV_NPD) { dst = wcat_bf + (size_t)160*DIN + j; }
  else { j -= CV_NPD; src = wdtp + j; dst = wdtp_bf + j; }
  u16x8 o = {};
  if (src) {
    f32x4 a = *(const f32x4*)src;
    f32x4 b = *(const f32x4*)(src + 4);
#pragma unroll
    for (int i = 0; i < 4; i++) { o[i] = f2bf(a[i]); o[4 + i] = f2bf(b[i]); }
  }
  *(u16x8*)dst = o;
}

// ---------------- pipelined NT GEMM: 128x128, BK=64, fp32 B with fused cvt ----------------
// A: [M][Kstride] bf16 (global_load_lds).  B: fp32 [.][Kstride] -- rows n0..
// come from Bf0 (row < 4096) or Bf1 (row-4096); staged global->VGPR, cvt to
// bf16 in-register, ds_write to swizzled LDS slots (T14 issue-early /
// write-late: loads issue before the MFMA phase, writes after it).
// Per K-step: {stage A(t+1) via global_load_lds; issue B(t+1) fp32 loads} ->
// compute(t) [16 ds_read_b128 + 32 MFMA] -> cvt+ds_write B(t+1) ->
// __syncthreads (drains vmcnt+lgkmcnt, one barrier/step).
// T2 swizzle (rows 128 B = 8 x 16 B slots): physical slot s of row r holds
// k-chunk s ^ (r&7). A: linear LDS dest => inverse-swizzled GLOBAL source
// (rule #21). B: reg-staged => swizzle applied directly on ds_write addr.
// Read slot (kk*4+lg) ^ (lr&7) on both. Banks: 2 lanes/bank (free).
// grid.z>1 => split-K. XCD swizzle needs gridDim.x*gridDim.y % 8 == 0.
// Requires Kiter % 64 == 0.
template<int EPI>
__global__ __launch_bounds__(256, 2) void gemm128(
    const unsigned short* __restrict__ Ag,
    const float* __restrict__ Bf0, const float* __restrict__ Bf1,
    float* __restrict__ Cg, const float* __restrict__ bias,
    int Msz, int Nsz, int Kstride, int Kiter)
{
  __shared__ __align__(16) unsigned short As[2][128 * 64];
  __shared__ __align__(16) unsigned short Bs[2][128 * 64];
  const int kz = blockIdx.z;
  Ag += (size_t)kz * Kiter;
  Cg += (size_t)kz * Msz * Nsz;
  const int nwg = gridDim.x * gridDim.y;
  const int orig = blockIdx.y * gridDim.x + blockIdx.x;
  const int swz = (orig & 7) * (nwg >> 3) + (orig >> 3);
  const int bx = swz % gridDim.x, by = swz / gridDim.x;
  const int tid = threadIdx.x;
  const int m0 = bx * 128, n0 = by * 128;
  const int lane = tid & 63, w = tid >> 6;
  const int wm = w >> 1, wn = w & 1;
  const int lg = lane >> 4, lr = lane & 15;

  // ---- A staging (global_load_lds, source-swizzled) ----
  const int srow = w * 32 + (lane >> 3);
  const int sslot = (lane & 7) ^ (lane >> 3);
  const unsigned short* Ag0 = Ag + (size_t)(m0 + srow) * Kstride + sslot * 8;
  const int ldso = w * 2048;
  auto stageA = [&](int b, int k0) {
#pragma unroll
    for (int i = 0; i < 4; i++)
      __builtin_amdgcn_global_load_lds(GPTR(Ag0 + (size_t)(i * 8) * Kstride + k0),
                                       LPTR(&As[b][ldso + i * 512]), 16, 0, 0);
  };

  // ---- B fp32 reg-staging: thread covers row=tid>>1, half (tid&1)*32 elems ----
  const int brow = tid >> 1;
  const int c0 = (tid & 1) * 4;                 // first 8-elem k-chunk index
  const float* Bbase = (n0 < 4096) ? (Bf0 + (size_t)n0 * Kstride)
                                   : (Bf1 + (size_t)(n0 - 4096) * Kstride);
  const float* Brow = Bbase + (size_t)brow * Kstride + (tid & 1) * 32 + (size_t)kz * Kiter;
  const int bws = brow & 7;                     // B write-side XOR key

  f32x4 ld[8];
  auto loadB = [&](int k0) {
#pragma unroll
    for (int j = 0; j < 8; j++) ld[j] = *(const f32x4*)(Brow + k0 + j * 4);
  };
  auto writeB = [&](int b) {
#pragma unroll
    for (int j = 0; j < 4; j++) {
      bf16x8v v;
      v[0] = (__bf16)ld[2 * j][0]; v[1] = (__bf16)ld[2 * j][1];
      v[2] = (__bf16)ld[2 * j][2]; v[3] = (__bf16)ld[2 * j][3];
      v[4] = (__bf16)ld[2 * j + 1][0]; v[5] = (__bf16)ld[2 * j + 1][1];
      v[6] = (__bf16)ld[2 * j + 1][2]; v[7] = (__bf16)ld[2 * j + 1][3];
      *(bf16x8v*)&Bs[b][brow * 64 + ((c0 + j) ^ bws) * 8] = v;
    }
  };

  const int rsw = lr & 7;                       // read-side XOR key
  f32x4 acc[4][4] = {};
  auto compute = [&](int b) {
    bf16x8v af0[4], af1[4], bf0[4], bf1[4];
#pragma unroll
    for (int mi = 0; mi < 4; mi++) {
      const int row = (wm * 64 + mi * 16 + lr) * 64;
      af0[mi] = *(const bf16x8v*)&As[b][row + (lg ^ rsw) * 8];
      af1[mi] = *(const bf16x8v*)&As[b][row + ((4 + lg) ^ rsw) * 8];
    }
#pragma unroll
    for (int ni = 0; ni < 4; ni++) {
      const int row = (wn * 64 + ni * 16 + lr) * 64;
      bf0[ni] = *(const bf16x8v*)&Bs[b][row + (lg ^ rsw) * 8];
      bf1[ni] = *(const bf16x8v*)&Bs[b][row + ((4 + lg) ^ rsw) * 8];
    }
#pragma unroll
    for (int mi = 0; mi < 4; mi++)
#pragma unroll
      for (int ni = 0; ni < 4; ni++)
        acc[mi][ni] = __builtin_amdgcn_mfma_f32_16x16x32_bf16(af0[mi], bf0[ni], acc[mi][ni], 0, 0, 0);
#pragma unroll
    for (int mi = 0; mi < 4; mi++)
#pragma unroll
      for (int ni = 0; ni < 4; ni++)
        acc[mi][ni] = __builtin_amdgcn_mfma_f32_16x16x32_bf16(af1[mi], bf1[ni], acc[mi][ni], 0, 0, 0);
  };

  const int nt = Kiter >> 6;
  // prologue: tile 0 (latency exposed once)
  stageA(0, 0);
  loadB(0);
  writeB(0);
  __syncthreads();
  int cur = 0;
  for (int t = 0; t < nt; ++t) {
    if (t + 1 < nt) { stageA(cur ^ 1, (t + 1) * 64); loadB((t + 1) * 64); }
    compute(cur);
    if (t + 1 < nt) writeB(cur ^ 1);
    __syncthreads();
    cur ^= 1;
  }
#pragma unroll
  for (int mi = 0; mi < 4; mi++) {
#pragma unroll
    for (int ni = 0; ni < 4; ni++) {
      const int col = n0 + wn * 64 + ni * 16 + lr;
#pragma unroll
      for (int r = 0; r < 4; r++) {
        const int row = m0 + wm * 64 + mi * 16 + lg * 4 + r;
        float v = acc[mi][ni][r];
        if (EPI == 1) v = softplus_f(v + bias[col]);
        Cg[(size_t)row * Nsz + col] = v;
      }
    }
  }
}

// ---------------- 128x64 NT GEMM, VGPR-staged (ts/B/C projection + dt-proj) ----------------
template<int EPI>
__global__ __launch_bounds__(256) void gemm_nt(
    const unsigned short* __restrict__ Ag, const unsigned short* __restrict__ Bg,
    float* __restrict__ Cg, const float* __restrict__ bias,
    int Msz, int Nsz, int Kstride, int Kiter)
{
  __shared__ __align__(16) unsigned short As[128][40];
  __shared__ __align__(16) unsigned short Bs[64][40];
  const int kz = blockIdx.z;
  Ag += (size_t)kz * Kiter;
  Bg += (size_t)kz * Kiter;
  Cg += (size_t)kz * Msz * Nsz;
  const int tid = threadIdx.x;
  const int m0 = blockIdx.x * 128, n0 = blockIdx.y * 64;
  const int lane = tid & 63, w = tid >> 6;
  const int wm = w >> 1, wn = w & 1;
  const int lg = lane >> 4, lr = lane & 15;
  const int r4 = tid >> 2, c8 = (tid & 3) * 8;
  f32x4 acc[4][2] = {};
  for (int k0 = 0; k0 < Kiter; k0 += 32) {
    uint4 a0 = *(const uint4*)(Ag + (size_t)(m0 + r4) * Kstride + k0 + c8);
    uint4 a1 = *(const uint4*)(Ag + (size_t)(m0 + 64 + r4) * Kstride + k0 + c8);
    uint4 b0 = *(const uint4*)(Bg + (size_t)(n0 + r4) * Kstride + k0 + c8);
    *(uint4*)&As[r4][c8] = a0;
    *(uint4*)&As[64 + r4][c8] = a1;
    *(uint4*)&Bs[r4][c8] = b0;
    __syncthreads();
    bf16x8v af[4], bfr[2];
#pragma unroll
    for (int mi = 0; mi < 4; mi++) {
      const int row = wm * 64 + mi * 16 + lr;
      bf16x4v lo = *(const bf16x4v*)&As[row][4 * lg];
      bf16x4v hi = *(const bf16x4v*)&As[row][16 + 4 * lg];
      af[mi] = __builtin_shufflevector(lo, hi, 0, 1, 2, 3, 4, 5, 6, 7);
    }
#pragma unroll
    for (int ni = 0; ni < 2; ni++) {
      const int row = wn * 32 + ni * 16 + lr;
      bf16x4v lo = *(const bf16x4v*)&Bs[row][4 * lg];
      bf16x4v hi = *(const bf16x4v*)&Bs[row][16 + 4 * lg];
      bfr[ni] = __builtin_shufflevector(lo, hi, 0, 1, 2, 3, 4, 5, 6, 7);
    }
#pragma unroll
    for (int mi = 0; mi < 4; mi++)
#pragma unroll
      for (int ni = 0; ni < 2; ni++)
        acc[mi][ni] = __builtin_amdgcn_mfma_f32_16x16x32_bf16(af[mi], bfr[ni], acc[mi][ni], 0, 0, 0);
    __syncthreads();
  }
#pragma unroll
  for (int mi = 0; mi < 4; mi++) {
#pragma unroll
    for (int ni = 0; ni < 2; ni++) {
      const int col = n0 + wn * 32 + ni * 16 + lr;
#pragma unroll
      for (int r = 0; r < 4; r++) {
        const int row = m0 + wm * 64 + mi * 16 + lg * 4 + r;
        float v = acc[mi][ni][r];
        if (EPI == 1) v = softplus_f(v + bias[col]);
        Cg[(size_t)row * Nsz + col] = v;
      }
    }
  }
}

// ---------------- causal depthwise conv(K=4) + bias + silu; pg stride 8192 ----------------
__global__ __launch_bounds__(256) void conv_silu(
    const float* __restrict__ pg, const float* __restrict__ cw,
    const float* __restrict__ cb, float* __restrict__ hs,
    unsigned short* __restrict__ hs_bf)
{
  int idx = blockIdx.x * 256 + threadIdx.x;  // l*DIN + d
  int l = idx >> 12, d = idx & (DIN - 1);
  float acc = cb[d];
#pragma unroll
  for (int j = 0; j < 4; j++) {
    int ll = l + j - 3;
    float v = (ll >= 0) ? pg[(size_t)ll * 8192 + d] : 0.f;
    acc = fmaf(cw[d * 4 + j], v, acc);
  }
  float r = silu_f(acc);
  hs[idx] = r;
  hs_bf[idx] = f2bf(r);
}

// ---------------- split-K reduce for ts/B/C + ts->bf16 ----------------
__global__ __launch_bounds__(256) void reduce_ts(
    const float* __restrict__ c2p, float* __restrict__ c2,
    unsigned short* __restrict__ ts_bf)
{
  int i = blockIdx.x * 256 + threadIdx.x;  // < SEQ*192
  float s = 0.f;
#pragma unroll
  for (int z = 0; z < 8; z++) s += c2p[(size_t)z * SEQ * 192 + i];
  c2[i] = s;
  int l = i / 192, col = i - l * 192;
  if (col < 128) ts_bf[l * 128 + col] = f2bf(s);
}

// ---------------- split-K reduce for out-proj (x4, float4) ----------------
__global__ __launch_bounds__(256) void reduce_out(
    const float* __restrict__ p, float* __restrict__ out)
{
  int i = (blockIdx.x * 256 + threadIdx.x) * 4;
  float4 a = *(const float4*)&p[i];
#pragma unroll
  for (int z = 1; z < 4; z++) {
    float4 b = *(const float4*)&p[(size_t)z * SEQ * HID + i];
    a.x += b.x; a.y += b.y; a.z += b.z; a.w += b.w;
  }
  *(float4*)&out[i] = a;
}

// ---------------- chunked selective scan ----------------
__global__ __launch_bounds__(256) void scan_phase1(
    const float* __restrict__ dt, const float* __restrict__ hs,
    const float* __restrict__ c2, const float* __restrict__ alog,
    float* __restrict__ Pbuf, float* __restrict__ Sbuf)
{
  __shared__ float B_ch[CLEN][16];
  const int tid = threadIdx.x;
  const int d = blockIdx.x * 256 + tid;
  const int c = blockIdx.y;
  const int l0 = c * CLEN;
  B_ch[tid >> 4][tid & 15] = c2[(size_t)(l0 + (tid >> 4)) * 192 + 128 + (tid & 15)];
  float a[16];
#pragma unroll
  for (int i = 0; i < 16; i++) a[i] = -__expf(alog[(size_t)d * 16 + i]);
  __syncthreads();
  float s[16] = {};
  float P[16];
#pragma unroll
  for (int i = 0; i < 16; i++) P[i] = 1.f;
  for (int t = 0; t < CLEN; t++) {
    float dtv = dt[(size_t)(l0 + t) * DIN + d];
    float u = hs[(size_t)(l0 + t) * DIN + d];
    float w = dtv * u;
#pragma unroll
    for (int n = 0; n < 16; n++) {
      float dA = __expf(a[n] * dtv);
      s[n] = fmaf(dA, s[n], w * B_ch[t][n]);
      P[n] *= dA;
    }
  }
  size_t base = ((size_t)c * DIN + d) * 16;
#pragma unroll
  for (int i = 0; i < 4; i++) {
    *(float4*)&Sbuf[base + 4 * i] = *(float4*)&s[4 * i];
    *(float4*)&Pbuf[base + 4 * i] = *(float4*)&P[4 * i];
  }
}

// phase 2: serial combine; sig written IN-PLACE into Sbuf
__global__ __launch_bounds__(256) void scan_phase2(
    const float* __restrict__ Pbuf, float* __restrict__ Sbuf)
{
  size_t idx = (size_t)blockIdx.x * 256 + threadIdx.x;  // d*16+n
  const size_t stride = (size_t)DIN * 16;
  float s = 0.f;
#pragma unroll 4
  for (int c = 0; c < CHN; c++) {
    float Pv = Pbuf[c * stride + idx];
    float Sv = Sbuf[c * stride + idx];
    Sbuf[c * stride + idx] = s;
    s = fmaf(Pv, s, Sv);
  }
}

// phase 3: re-scan chunk from sig (=Sbuf), y = s.C, fused D + gate, write ygT bf16
__global__ __launch_bounds__(256) void scan_phase3(
    const float* __restrict__ dt, const float* __restrict__ hs,
    const float* __restrict__ pg, const float* __restrict__ c2,
    const float* __restrict__ alog, const float* __restrict__ Dv,
    const float* __restrict__ sig, unsigned short* __restrict__ ygT)
{
  __shared__ float B_ch[CLEN][16], C_ch[CLEN][16];
  const int tid = threadIdx.x;
  const int d = blockIdx.x * 256 + tid;
  const int c = blockIdx.y;
  const int l0 = c * CLEN;
  {
    int t = tid >> 4, n = tid & 15;
    B_ch[t][n] = c2[(size_t)(l0 + t) * 192 + 128 + n];
    C_ch[t][n] = c2[(size_t)(l0 + t) * 192 + 144 + n];
  }
  float a[16];
#pragma unroll
  for (int i = 0; i < 16; i++) a[i] = -__expf(alog[(size_t)d * 16 + i]);
  const float Dd = Dv[d];
  float s[16];
  size_t base = ((size_t)c * DIN + d) * 16;
#pragma unroll
  for (int i = 0; i < 4; i++) *(float4*)&s[4 * i] = *(const float4*)&sig[base + 4 * i];
  __syncthreads();
  for (int t = 0; t < CLEN; t++) {
    float dtv = dt[(size_t)(l0 + t) * DIN + d];
    float u = hs[(size_t)(l0 + t) * DIN + d];
    float g = pg[(size_t)(l0 + t) * 8192 + 4096 + d];
    float w = dtv * u;
    float y = 0.f;
#pragma unroll
    for (int n = 0; n < 16; n++) {
      float dA = __expf(a[n] * dtv);
      s[n] = fmaf(dA, s[n], w * B_ch[t][n]);
      y = fmaf(s[n], C_ch[t][n], y);
    }
    float o = (y + u * Dd) * silu_f(g);
    ygT[(size_t)(l0 + t) * DIN + d] = f2bf(o);
  }
}

extern "C" void kernel_launch(void* const* d_in, const int* in_sizes, int n_in,
                              void* d_out, int out_size, void* d_ws, size_t ws_size,
                              hipStream_t stream) {
  const float* x     = (const float*)d_in[0];
  const float* wis   = (const float*)d_in[1];
  const float* wig   = (const float*)d_in[2];
  const float* convw = (const float*)d_in[3];
  const float* convb = (const float*)d_in[4];
  const float* wdt   = (const float*)d_in[5];
  const float* wb    = (const float*)d_in[6];
  const float* wc    = (const float*)d_in[7];
  const float* wdtp  = (const float*)d_in[8];
  const float* bdtp  = (const float*)d_in[9];
  const float* alog  = (const float*)d_in[10];
  const float* Dv    = (const float*)d_in[11];
  const float* wout  = (const float*)d_in[12];

  char* ws = (char*)d_ws;
  size_t off = 0;
  auto alloc = [&](size_t bytes) { void* p = ws + off; off += (bytes + 255) & ~(size_t)255; return p; };
  unsigned short* x_bf    = (unsigned short*)alloc((size_t)SEQ * HID * 2);
  unsigned short* wcat_bf = (unsigned short*)alloc((size_t)192 * DIN * 2);
  unsigned short* wdtp_bf = (unsigned short*)alloc((size_t)DIN * RNK * 2);
  float* pg    = (float*)alloc((size_t)SEQ * 8192 * 4);  // [SEQ][8192]: cols 0..4095 pre-conv states, 4096..8191 gate
  float* hs2   = (float*)alloc((size_t)SEQ * DIN * 4);   // hs post conv+silu [SEQ][DIN]
  unsigned short* hs_bf = (unsigned short*)alloc((size_t)SEQ * DIN * 2);
  float* c2    = (float*)alloc((size_t)SEQ * 192 * 4);
  float* c2p   = (float*)alloc((size_t)8 * SEQ * 192 * 4);
  unsigned short* ts_bf = (unsigned short*)alloc((size_t)SEQ * RNK * 2);
  float* dtbuf = (float*)alloc((size_t)SEQ * DIN * 4);
  unsigned short* ygT_bf = (unsigned short*)alloc((size_t)SEQ * DIN * 2);
  float* Pbuf  = (float*)alloc((size_t)CHN * DIN * NST * 4);
  float* Sbuf  = (float*)alloc((size_t)CHN * DIN * NST * 4);  // phase2 overwrites with sig in-place
  if (off > ws_size) return;  // workspace too small: fail loudly via validation
  // dead-buffer reuse: pg (32 MB) dead after scan_phase3 -> 4 out-proj partials.
  float* op_part = pg;            // [4][SEQ][HID]

  // 1) bf16 conversions for x + small weights only (weights for the two big
  //    GEMMs are consumed as fp32 directly)
  cvt_all<<<CV_TOT / 2048, 256, 0, stream>>>(x, wdt, wb, wc, wdtp,
                                             x_bf, wcat_bf, wdtp_bf);
  // 2) merged input projection (BK=64 pipelined gemm, fp32-B fused cvt, XCD swizzle):
  //    pg[SEQ][8192] = x[SEQ][HID] x [wis;wig][8192][HID]
  gemm128<0><<<dim3(SEQ / 128, 8192 / 128), 256, 0, stream>>>(x_bf, wis, wig, pg, nullptr, SEQ, 8192, HID, HID);
  // 3) causal conv + silu + bf16 cast
  conv_silu<<<(SEQ * DIN) / 256, 256, 0, stream>>>(pg, convw, convb, hs2, hs_bf);
  // 4) ts/B/C projections, split-K x8
  gemm_nt<0><<<dim3(SEQ / 128, 192 / 64, 8), 256, 0, stream>>>(hs_bf, wcat_bf, c2p, nullptr, SEQ, 192, DIN, DIN / 8);
  reduce_ts<<<(SEQ * 192) / 256, 256, 0, stream>>>(c2p, c2, ts_bf);
  // 5) dt[SEQ][DIN] = softplus(ts[SEQ][RNK] x Wdtproj[DIN][RNK] + b)
  gemm_nt<1><<<dim3(SEQ / 128, DIN / 64), 256, 0, stream>>>(ts_bf, wdtp_bf, dtbuf, bdtp, SEQ, DIN, RNK, RNK);
  // 6) chunked selective scan (64 chunks of 16)
  scan_phase1<<<dim3(DIN / 256, CHN), 256, 0, stream>>>(dtbuf, hs2, c2, alog, Pbuf, Sbuf);
  scan_phase2<<<(DIN * NST) / 256, 256, 0, stream>>>(Pbuf, Sbuf);
  scan_phase3<<<dim3(DIN / 256, CHN), 256, 0, stream>>>(dtbuf, hs2, pg, c2, alog, Dv, Sbuf, ygT_bf);
  // 7) out-proj split-K x4 (512 wg): op_part[z][SEQ][HID] = ygT x Wout fp32 slices (K=1024)
  gemm128<0><<<dim3(SEQ / 128, HID / 128, 4), 256, 0, stream>>>(ygT_bf, wout, wout, op_part, nullptr, SEQ, HID, DIN, DIN / 4);
  reduce_out<<<(SEQ * HID) / 1024, 256, 0, stream>>>(op_part, (float*)d_out);
}

// Round 8
// 215.586 us; speedup vs baseline: 1.2121x; 1.1434x over previous
//
#include <hip/hip_runtime.h>

#define SEQ 1024
#define HID 2048
#define DIN 4096
#define NST 16
#define RNK 128
#define CHN 64
#define CLEN 16

typedef __attribute__((ext_vector_type(4))) float f32x4;
typedef __attribute__((ext_vector_type(4))) __bf16 bf16x4v;
typedef __attribute__((ext_vector_type(8))) __bf16 bf16x8v;
typedef __attribute__((ext_vector_type(8))) unsigned short u16x8;

#define GPTR(p) ((const __attribute__((address_space(1))) void*)(p))
#define LPTR(p) ((__attribute__((address_space(3))) void*)(p))

__device__ __forceinline__ unsigned short f2bf(float v) {
  unsigned u = __builtin_bit_cast(unsigned, v);
  u = (u + 0x7fffu + ((u >> 16) & 1u)) >> 16;
  return (unsigned short)u;
}
__device__ __forceinline__ float softplus_f(float x) {
  return (x > 20.f) ? x : log1pf(__expf(x));
}
__device__ __forceinline__ float silu_f(float x) {
  return x / (1.f + __expf(-x));
}

// ---------------- fp32 -> bf16 conversions, one launch, 16 elems/thread ----------------
#define CV_NX  (SEQ*HID)
#define CV_NW  (DIN*HID)
#define CV_NDT (RNK*DIN)
#define CV_NB  (NST*DIN)
#define CV_NPD (32*DIN)
#define CV_NWO (HID*DIN)
#define CV_TOT (CV_NX + 2*CV_NW + CV_NDT + 2*CV_NB + CV_NPD + CV_NDT + CV_NWO)

// All segment sizes are multiples of 1024, so no wave straddles a segment
// boundary (64 lanes x 16 elems = 1024). 64B load / 32B store per lane:
// 4 independent loads in flight per thread for latency hiding.
__global__ __launch_bounds__(256) void cvt_all(
    const float* __restrict__ x, const float* __restrict__ wis,
    const float* __restrict__ wig, const float* __restrict__ wdt,
    const float* __restrict__ wb, const float* __restrict__ wc,
    const float* __restrict__ wdtp, const float* __restrict__ wout,
    unsigned short* __restrict__ x_bf, unsigned short* __restrict__ wis_bf,
    unsigned short* __restrict__ wig_bf, unsigned short* __restrict__ wcat_bf,
    unsigned short* __restrict__ wdtp_bf, unsigned short* __restrict__ wout_bf)
{
  size_t j = ((size_t)blockIdx.x * 256 + threadIdx.x) * 16;
  const float* src = nullptr; unsigned short* dst;
  if (j < CV_NX) { src = x + j; dst = x_bf + j; }
  else if ((j -= CV_NX) < CV_NW) { src = wis + j; dst = wis_bf + j; }
  else if ((j -= CV_NW) < CV_NW) { src = wig + j; dst = wig_bf + j; }
  else if ((j -= CV_NW) < CV_NDT) { src = wdt + j; dst = wcat_bf + j; }
  else if ((j -= CV_NDT) < CV_NB) { src = wb + j; dst = wcat_bf + (size_t)128*DIN + j; }
  else if ((j -= CV_NB) < CV_NB) { src = wc + j; dst = wcat_bf + (size_t)144*DIN + j; }
  else if ((j -= CV_NB) < CV_NPD) { dst = wcat_bf + (size_t)160*DIN + j; }
  else if ((j -= CV_NPD) < CV_NDT) { src = wdtp + j; dst = wdtp_bf + j; }
  else { j -= CV_NDT; src = wout + j; dst = wout_bf + j; }
  u16x8 o0 = {}, o1 = {};
  if (src) {
    f32x4 a = *(const f32x4*)src;
    f32x4 b = *(const f32x4*)(src + 4);
    f32x4 c = *(const f32x4*)(src + 8);
    f32x4 d = *(const f32x4*)(src + 12);
#pragma unroll
    for (int i = 0; i < 4; i++) {
      o0[i] = f2bf(a[i]); o0[4 + i] = f2bf(b[i]);
      o1[i] = f2bf(c[i]); o1[4 + i] = f2bf(d[i]);
    }
  }
  *(u16x8*)dst = o0;
  *(u16x8*)(dst + 8) = o1;
}

// ---------------- pipelined NT GEMM: 128x128 tile, BK=64, 2 LDS buffers ----------------
// A: [M][Kstride] bf16, B: [N][Kstride] bf16, C: [M][N] fp32.
// Per K-step (one barrier): vmcnt(0) [tile t landed -- its loads had a FULL
// previous step in flight]; s_barrier; stage tile t+1 into buf^1 (safe: buf^1
// was last read in step t-1, fenced by this barrier); 16x ds_read_b128 +
// 32x MFMA on buf[cur]. BK=64 halves the step count vs BK=32: 2x work per
// synchronization point (the latency-bound cost at 2 blocks/CU).
// LDS 64 KB -> 2 blocks/CU, which equals the grid-imposed residency anyway.
// T2 swizzle, 8 slots/row (rows are 128 B = 8 x 16 B slots): physical slot
// s at row r holds global k-chunk s ^ (r&7). global_load_lds writes linearly
// (dest = base + lane*16, row r&7 = lane>>3), so the swizzle is applied on
// the GLOBAL source slot (lane&7)^(lane>>3) (rule #21); read slot is
// (kk*4+lg)^(lr&7). Banks: 2 lanes/bank (free minimum).
// grid.z>1 => split-K. XCD swizzle needs gridDim.x*gridDim.y % 8 == 0.
// Requires Kiter % 64 == 0, Kiter >= 128.
template<int EPI>
__global__ __launch_bounds__(256) void gemm128(
    const unsigned short* __restrict__ Ag, const unsigned short* __restrict__ Bg,
    float* __restrict__ Cg, const float* __restrict__ bias,
    int Msz, int Nsz, int Kstride, int Kiter)
{
  __shared__ __align__(16) unsigned short As[2][128 * 64];
  __shared__ __align__(16) unsigned short Bs[2][128 * 64];
  const int kz = blockIdx.z;
  Ag += (size_t)kz * Kiter;
  Bg += (size_t)kz * Kiter;
  Cg += (size_t)kz * Msz * Nsz;
  const int nwg = gridDim.x * gridDim.y;
  const int orig = blockIdx.y * gridDim.x + blockIdx.x;
  const int swz = (orig & 7) * (nwg >> 3) + (orig >> 3);
  const int bx = swz % gridDim.x, by = swz / gridDim.x;
  const int tid = threadIdx.x;
  const int m0 = bx * 128, n0 = by * 128;
  const int lane = tid & 63, w = tid >> 6;
  const int wm = w >> 1, wn = w & 1;
  const int lg = lane >> 4, lr = lane & 15;
  // staging: thread covers rows w*32 + i*8 + (lane>>3), i=0..3; 16B per lane.
  const int srow = w * 32 + (lane >> 3);
  const int sslot = (lane & 7) ^ (lane >> 3);      // swizzled global k-slot
  const unsigned short* Ag0 = Ag + (size_t)(m0 + srow) * Kstride + sslot * 8;
  const unsigned short* Bg0 = Bg + (size_t)(n0 + srow) * Kstride + sslot * 8;
  const int ldso = w * 2048;                        // ushort idx of wave chunk

  auto stage = [&](int b, int k0) {
#pragma unroll
    for (int i = 0; i < 4; i++)
      __builtin_amdgcn_global_load_lds(GPTR(Ag0 + (size_t)(i * 8) * Kstride + k0),
                                       LPTR(&As[b][ldso + i * 512]), 16, 0, 0);
#pragma unroll
    for (int i = 0; i < 4; i++)
      __builtin_amdgcn_global_load_lds(GPTR(Bg0 + (size_t)(i * 8) * Kstride + k0),
                                       LPTR(&Bs[b][ldso + i * 512]), 16, 0, 0);
  };

  const int nt = Kiter >> 6;
  stage(0, 0);
  f32x4 acc[4][4] = {};
  int cur = 0;
  const int rsw = lr & 7;                           // read-side XOR key
  for (int t = 0; t < nt; ++t) {
    asm volatile("s_waitcnt vmcnt(0)" ::: "memory");
    __builtin_amdgcn_s_barrier();
    asm volatile("" ::: "memory");
    if (t + 1 < nt) stage(cur ^ 1, (t + 1) * 64);
    bf16x8v af0[4], bf0[4], af1[4], bf1[4];
#pragma unroll
    for (int mi = 0; mi < 4; mi++) {
      const int row = (wm * 64 + mi * 16 + lr) * 64;
      af0[mi] = *(const bf16x8v*)&As[cur][row + ((0 * 4 + lg) ^ rsw) * 8];
      af1[mi] = *(const bf16x8v*)&As[cur][row + ((1 * 4 + lg) ^ rsw) * 8];
    }
#pragma unroll
    for (int ni = 0; ni < 4; ni++) {
      const int row = (wn * 64 + ni * 16 + lr) * 64;
      bf0[ni] = *(const bf16x8v*)&Bs[cur][row + ((0 * 4 + lg) ^ rsw) * 8];
      bf1[ni] = *(const bf16x8v*)&Bs[cur][row + ((1 * 4 + lg) ^ rsw) * 8];
    }
#pragma unroll
    for (int mi = 0; mi < 4; mi++)
#pragma unroll
      for (int ni = 0; ni < 4; ni++)
        acc[mi][ni] = __builtin_amdgcn_mfma_f32_16x16x32_bf16(af0[mi], bf0[ni], acc[mi][ni], 0, 0, 0);
#pragma unroll
    for (int mi = 0; mi < 4; mi++)
#pragma unroll
      for (int ni = 0; ni < 4; ni++)
        acc[mi][ni] = __builtin_amdgcn_mfma_f32_16x16x32_bf16(af1[mi], bf1[ni], acc[mi][ni], 0, 0, 0);
    cur ^= 1;
  }
#pragma unroll
  for (int mi = 0; mi < 4; mi++) {
#pragma unroll
    for (int ni = 0; ni < 4; ni++) {
      const int col = n0 + wn * 64 + ni * 16 + lr;
#pragma unroll
      for (int r = 0; r < 4; r++) {
        const int row = m0 + wm * 64 + mi * 16 + lg * 4 + r;
        float v = acc[mi][ni][r];
        if (EPI == 1) v = softplus_f(v + bias[col]);
        Cg[(size_t)row * Nsz + col] = v;
      }
    }
  }
}

// ---------------- 128x64 NT GEMM, VGPR-staged (ts/B/C projection + dt-proj) ----------------
template<int EPI>
__global__ __launch_bounds__(256) void gemm_nt(
    const unsigned short* __restrict__ Ag, const unsigned short* __restrict__ Bg,
    float* __restrict__ Cg, const float* __restrict__ bias,
    int Msz, int Nsz, int Kstride, int Kiter)
{
  __shared__ __align__(16) unsigned short As[128][40];
  __shared__ __align__(16) unsigned short Bs[64][40];
  const int kz = blockIdx.z;
  Ag += (size_t)kz * Kiter;
  Bg += (size_t)kz * Kiter;
  Cg += (size_t)kz * Msz * Nsz;
  const int tid = threadIdx.x;
  const int m0 = blockIdx.x * 128, n0 = blockIdx.y * 64;
  const int lane = tid & 63, w = tid >> 6;
  const int wm = w >> 1, wn = w & 1;
  const int lg = lane >> 4, lr = lane & 15;
  const int r4 = tid >> 2, c8 = (tid & 3) * 8;
  f32x4 acc[4][2] = {};
  for (int k0 = 0; k0 < Kiter; k0 += 32) {
    uint4 a0 = *(const uint4*)(Ag + (size_t)(m0 + r4) * Kstride + k0 + c8);
    uint4 a1 = *(const uint4*)(Ag + (size_t)(m0 + 64 + r4) * Kstride + k0 + c8);
    uint4 b0 = *(const uint4*)(Bg + (size_t)(n0 + r4) * Kstride + k0 + c8);
    *(uint4*)&As[r4][c8] = a0;
    *(uint4*)&As[64 + r4][c8] = a1;
    *(uint4*)&Bs[r4][c8] = b0;
    __syncthreads();
    bf16x8v af[4], bfr[2];
#pragma unroll
    for (int mi = 0; mi < 4; mi++) {
      const int row = wm * 64 + mi * 16 + lr;
      bf16x4v lo = *(const bf16x4v*)&As[row][4 * lg];
      bf16x4v hi = *(const bf16x4v*)&As[row][16 + 4 * lg];
      af[mi] = __builtin_shufflevector(lo, hi, 0, 1, 2, 3, 4, 5, 6, 7);
    }
#pragma unroll
    for (int ni = 0; ni < 2; ni++) {
      const int row = wn * 32 + ni * 16 + lr;
      bf16x4v lo = *(const bf16x4v*)&Bs[row][4 * lg];
      bf16x4v hi = *(const bf16x4v*)&Bs[row][16 + 4 * lg];
      bfr[ni] = __builtin_shufflevector(lo, hi, 0, 1, 2, 3, 4, 5, 6, 7);
    }
#pragma unroll
    for (int mi = 0; mi < 4; mi++)
#pragma unroll
      for (int ni = 0; ni < 2; ni++)
        acc[mi][ni] = __builtin_amdgcn_mfma_f32_16x16x32_bf16(af[mi], bfr[ni], acc[mi][ni], 0, 0, 0);
    __syncthreads();
  }
#pragma unroll
  for (int mi = 0; mi < 4; mi++) {
#pragma unroll
    for (int ni = 0; ni < 2; ni++) {
      const int col = n0 + wn * 32 + ni * 16 + lr;
#pragma unroll
      for (int r = 0; r < 4; r++) {
        const int row = m0 + wm * 64 + mi * 16 + lg * 4 + r;
        float v = acc[mi][ni][r];
        if (EPI == 1) v = softplus_f(v + bias[col]);
        Cg[(size_t)row * Nsz + col] = v;
      }
    }
  }
}

// ---------------- causal depthwise conv(K=4) + bias + silu; pg stride 8192 ----------------
__global__ __launch_bounds__(256) void conv_silu(
    const float* __restrict__ pg, const float* __restrict__ cw,
    const float* __restrict__ cb, float* __restrict__ hs,
    unsigned short* __restrict__ hs_bf)
{
  int idx = blockIdx.x * 256 + threadIdx.x;  // l*DIN + d
  int l = idx >> 12, d = idx & (DIN - 1);
  float acc = cb[d];
#pragma unroll
  for (int j = 0; j < 4; j++) {
    int ll = l + j - 3;
    float v = (ll >= 0) ? pg[(size_t)ll * 8192 + d] : 0.f;
    acc = fmaf(cw[d * 4 + j], v, acc);
  }
  float r = silu_f(acc);
  hs[idx] = r;
  hs_bf[idx] = f2bf(r);
}

// ---------------- split-K reduce for ts/B/C + ts->bf16 ----------------
__global__ __launch_bounds__(256) void reduce_ts(
    const float* __restrict__ c2p, float* __restrict__ c2,
    unsigned short* __restrict__ ts_bf)
{
  int i = blockIdx.x * 256 + threadIdx.x;  // < SEQ*192
  float s = 0.f;
#pragma unroll
  for (int z = 0; z < 8; z++) s += c2p[(size_t)z * SEQ * 192 + i];
  c2[i] = s;
  int l = i / 192, col = i - l * 192;
  if (col < 128) ts_bf[l * 128 + col] = f2bf(s);
}

// ---------------- split-K reduce for out-proj (x4, float4) ----------------
__global__ __launch_bounds__(256) void reduce_out(
    const float* __restrict__ p, float* __restrict__ out)
{
  int i = (blockIdx.x * 256 + threadIdx.x) * 4;
  float4 a = *(const float4*)&p[i];
#pragma unroll
  for (int z = 1; z < 4; z++) {
    float4 b = *(const float4*)&p[(size_t)z * SEQ * HID + i];
    a.x += b.x; a.y += b.y; a.z += b.z; a.w += b.w;
  }
  *(float4*)&out[i] = a;
}

// ---------------- chunked selective scan ----------------
__global__ __launch_bounds__(256) void scan_phase1(
    const float* __restrict__ dt, const float* __restrict__ hs,
    const float* __restrict__ c2, const float* __restrict__ alog,
    float* __restrict__ Pbuf, float* __restrict__ Sbuf)
{
  __shared__ float B_ch[CLEN][16];
  const int tid = threadIdx.x;
  const int d = blockIdx.x * 256 + tid;
  const int c = blockIdx.y;
  const int l0 = c * CLEN;
  B_ch[tid >> 4][tid & 15] = c2[(size_t)(l0 + (tid >> 4)) * 192 + 128 + (tid & 15)];
  float a[16];
#pragma unroll
  for (int i = 0; i < 16; i++) a[i] = -__expf(alog[(size_t)d * 16 + i]);
  __syncthreads();
  float s[16] = {};
  float P[16];
#pragma unroll
  for (int i = 0; i < 16; i++) P[i] = 1.f;
  for (int t = 0; t < CLEN; t++) {
    float dtv = dt[(size_t)(l0 + t) * DIN + d];
    float u = hs[(size_t)(l0 + t) * DIN + d];
    float w = dtv * u;
#pragma unroll
    for (int n = 0; n < 16; n++) {
      float dA = __expf(a[n] * dtv);
      s[n] = fmaf(dA, s[n], w * B_ch[t][n]);
      P[n] *= dA;
    }
  }
  size_t base = ((size_t)c * DIN + d) * 16;
#pragma unroll
  for (int i = 0; i < 4; i++) {
    *(float4*)&Sbuf[base + 4 * i] = *(float4*)&s[4 * i];
    *(float4*)&Pbuf[base + 4 * i] = *(float4*)&P[4 * i];
  }
}

// phase 2: serial combine; sig written IN-PLACE into Sbuf
__global__ __launch_bounds__(256) void scan_phase2(
    const float* __restrict__ Pbuf, float* __restrict__ Sbuf)
{
  size_t idx = (size_t)blockIdx.x * 256 + threadIdx.x;  // d*16+n
  const size_t stride = (size_t)DIN * 16;
  float s = 0.f;
#pragma unroll 4
  for (int c = 0; c < CHN; c++) {
    float Pv = Pbuf[c * stride + idx];
    float Sv = Sbuf[c * stride + idx];
    Sbuf[c * stride + idx] = s;
    s = fmaf(Pv, s, Sv);
  }
}

// phase 3: re-scan chunk from sig (=Sbuf), y = s.C, fused D + gate, write ygT bf16
__global__ __launch_bounds__(256) void scan_phase3(
    const float* __restrict__ dt, const float* __restrict__ hs,
    const float* __restrict__ pg, const float* __restrict__ c2,
    const float* __restrict__ alog, const float* __restrict__ Dv,
    const float* __restrict__ sig, unsigned short* __restrict__ ygT)
{
  __shared__ float B_ch[CLEN][16], C_ch[CLEN][16];
  const int tid = threadIdx.x;
  const int d = blockIdx.x * 256 + tid;
  const int c = blockIdx.y;
  const int l0 = c * CLEN;
  {
    int t = tid >> 4, n = tid & 15;
    B_ch[t][n] = c2[(size_t)(l0 + t) * 192 + 128 + n];
    C_ch[t][n] = c2[(size_t)(l0 + t) * 192 + 144 + n];
  }
  float a[16];
#pragma unroll
  for (int i = 0; i < 16; i++) a[i] = -__expf(alog[(size_t)d * 16 + i]);
  const float Dd = Dv[d];
  float s[16];
  size_t base = ((size_t)c * DIN + d) * 16;
#pragma unroll
  for (int i = 0; i < 4; i++) *(float4*)&s[4 * i] = *(const float4*)&sig[base + 4 * i];
  __syncthreads();
  for (int t = 0; t < CLEN; t++) {
    float dtv = dt[(size_t)(l0 + t) * DIN + d];
    float u = hs[(size_t)(l0 + t) * DIN + d];
    float g = pg[(size_t)(l0 + t) * 8192 + 4096 + d];
    float w = dtv * u;
    float y = 0.f;
#pragma unroll
    for (int n = 0; n < 16; n++) {
      float dA = __expf(a[n] * dtv);
      s[n] = fmaf(dA, s[n], w * B_ch[t][n]);
      y = fmaf(s[n], C_ch[t][n], y);
    }
    float o = (y + u * Dd) * silu_f(g);
    ygT[(size_t)(l0 + t) * DIN + d] = f2bf(o);
  }
}

extern "C" void kernel_launch(void* const* d_in, const int* in_sizes, int n_in,
                              void* d_out, int out_size, void* d_ws, size_t ws_size,
                              hipStream_t stream) {
  const float* x     = (const float*)d_in[0];
  const float* wis   = (const float*)d_in[1];
  const float* wig   = (const float*)d_in[2];
  const float* convw = (const float*)d_in[3];
  const float* convb = (const float*)d_in[4];
  const float* wdt   = (const float*)d_in[5];
  const float* wb    = (const float*)d_in[6];
  const float* wc    = (const float*)d_in[7];
  const float* wdtp  = (const float*)d_in[8];
  const float* bdtp  = (const float*)d_in[9];
  const float* alog  = (const float*)d_in[10];
  const float* Dv    = (const float*)d_in[11];
  const float* wout  = (const float*)d_in[12];

  char* ws = (char*)d_ws;
  size_t off = 0;
  auto alloc = [&](size_t bytes) { void* p = ws + off; off += (bytes + 255) & ~(size_t)255; return p; };
  unsigned short* x_bf    = (unsigned short*)alloc((size_t)SEQ * HID * 2);
  unsigned short* wis_bf  = (unsigned short*)alloc((size_t)DIN * HID * 2);  // adjacent to wig_bf: one [8192][2048] B matrix
  unsigned short* wig_bf  = (unsigned short*)alloc((size_t)DIN * HID * 2);
  unsigned short* wcat_bf = (unsigned short*)alloc((size_t)192 * DIN * 2);
  unsigned short* wdtp_bf = (unsigned short*)alloc((size_t)DIN * RNK * 2);
  unsigned short* wout_bf = (unsigned short*)alloc((size_t)HID * DIN * 2);
  float* pg    = (float*)alloc((size_t)SEQ * 8192 * 4);  // [SEQ][8192]: cols 0..4095 pre-conv states, 4096..8191 gate
  float* hs2   = (float*)alloc((size_t)SEQ * DIN * 4);   // hs post conv+silu [SEQ][DIN]
  unsigned short* hs_bf = (unsigned short*)alloc((size_t)SEQ * DIN * 2);
  float* c2    = (float*)alloc((size_t)SEQ * 192 * 4);
  float* c2p   = (float*)alloc((size_t)8 * SEQ * 192 * 4);
  unsigned short* ts_bf = (unsigned short*)alloc((size_t)SEQ * RNK * 2);
  float* dtbuf = (float*)alloc((size_t)SEQ * DIN * 4);
  unsigned short* ygT_bf = (unsigned short*)alloc((size_t)SEQ * DIN * 2);
  if (off > ws_size) return;  // workspace too small: fail loudly via validation
  // dead-buffer reuse: wis_bf/wig_bf (16 MB each) dead after in-proj;
  // pg (32 MB) dead after scan_phase3 -> holds the 4 out-proj partials.
  float* Pbuf = (float*)wis_bf;
  float* Sbuf = (float*)wig_bf;   // phase2 overwrites with sig in-place
  float* op_part = pg;            // [4][SEQ][HID] out-proj partials

  // 1) all bf16 conversions (16 elems/thread: 4x float4 load, 2x ushort8 store)
  cvt_all<<<CV_TOT / 4096, 256, 0, stream>>>(x, wis, wig, wdt, wb, wc, wdtp, wout,
                                             x_bf, wis_bf, wig_bf, wcat_bf, wdtp_bf, wout_bf);
  // 2) merged input projection (BK=64 pipelined gemm, XCD swizzle):
  //    pg[SEQ][8192] = x[SEQ][HID] x [wis;wig][8192][HID]
  gemm128<0><<<dim3(SEQ / 128, 8192 / 128), 256, 0, stream>>>(x_bf, wis_bf, pg, nullptr, SEQ, 8192, HID, HID);
  // 3) causal conv + silu + bf16 cast
  conv_silu<<<(SEQ * DIN) / 256, 256, 0, stream>>>(pg, convw, convb, hs2, hs_bf);
  // 4) ts/B/C projections, split-K x8
  gemm_nt<0><<<dim3(SEQ / 128, 192 / 64, 8), 256, 0, stream>>>(hs_bf, wcat_bf, c2p, nullptr, SEQ, 192, DIN, DIN / 8);
  reduce_ts<<<(SEQ * 192) / 256, 256, 0, stream>>>(c2p, c2, ts_bf);
  // 5) dt[SEQ][DIN] = softplus(ts[SEQ][RNK] x Wdtproj[DIN][RNK] + b)
  gemm_nt<1><<<dim3(SEQ / 128, DIN / 64), 256, 0, stream>>>(ts_bf, wdtp_bf, dtbuf, bdtp, SEQ, DIN, RNK, RNK);
  // 6) chunked selective scan (64 chunks of 16)
  scan_phase1<<<dim3(DIN / 256, CHN), 256, 0, stream>>>(dtbuf, hs2, c2, alog, Pbuf, Sbuf);
  scan_phase2<<<(DIN * NST) / 256, 256, 0, stream>>>(Pbuf, Sbuf);
  scan_phase3<<<dim3(DIN / 256, CHN), 256, 0, stream>>>(dtbuf, hs2, pg, c2, alog, Dv, Sbuf, ygT_bf);
  // 7) out-proj split-K x4 (512 wg): op_part[z][SEQ][HID] = ygT x Wout slices (K=1024, nt=16)
  gemm128<0><<<dim3(SEQ / 128, HID / 128, 4), 256, 0, stream>>>(ygT_bf, wout_bf, op_part, nullptr, SEQ, HID, DIN, DIN / 4);
  reduce_out<<<(SEQ * HID) / 1024, 256, 0, stream>>>(op_part, (float*)d_out);
}